// Round 5
// baseline (307.476 us; speedup 1.0000x reference)
//
#include <hip/hip_runtime.h>
#include <math.h>

#define B_     1024
#define T_     80
#define D_     512
#define C_     78      // VOCAB+1
#define PRED_  30
#define BLANK_ 77
#define NKK    16      // 512 / 32
#define FRAG   512     // ushorts per fragment block (64 lanes * 8 f16)
#define PLANE_STRIDE (5 * NKK * FRAG)   // 40960 ushorts per plane

typedef __attribute__((ext_vector_type(8))) _Float16 f16x8;
typedef __attribute__((ext_vector_type(4))) float    f32x4;

// Split W [512,78] fp32 into two f16 planes (w1 = rnd(w), w2 = rnd(w - w1)),
// fragment-linear: [plane][ct][kk][lane][j] -> main-loop B load = base + lane*16B.
__global__ __launch_bounds__(256) void prep_w(const float* __restrict__ W,
                                              ushort* __restrict__ Wf) {
    int i = blockIdx.x * 256 + threadIdx.x;
    if (i >= 2 * PLANE_STRIDE) return;
    int j    = i & 7;
    int lane = (i >> 3) & 63;
    int kk   = (i >> 9) & 15;
    int rest = i >> 13;          // plane*5 + ct
    int ct   = rest % 5;
    int plane = rest / 5;
    int q = lane >> 4, n = lane & 15;
    int k = kk * 32 + q * 8 + j;
    int c = ct * 16 + n;
    float v = (c < C_) ? W[k * C_ + c] : 0.f;
    _Float16 h1 = (_Float16)v;
    union { _Float16 h; ushort u; } cv;
    cv.h = (plane == 0) ? h1 : (_Float16)(v - (float)h1);
    Wf[i] = cv.u;
}

// Barrier-free GEMM: wave = 32 rows (2 MFMA tiles), K in BK=64 super-steps,
// A register double-buffered (256 B contiguous per row-visit), B from L2/L1.
// No LDS. C/D layout: col = lane&15, row = (lane>>4)*4 + reg.
__global__ __launch_bounds__(256, 3) void gemm_fused(
    const float* __restrict__ feat,   // [81920, 512] fp32
    const ushort* __restrict__ Wf,    // f16 split planes, fragment-linear
    const float* __restrict__ bias,   // [78] fp32
    float* __restrict__ probs,        // [81920, 78] fp32
    int*   __restrict__ best)         // [81920]
{
    const int tid  = threadIdx.x;
    const int w    = tid >> 6;
    const int lane = tid & 63;
    const int q    = lane >> 4;
    const int n    = lane & 15;
    const int wid  = blockIdx.x * 4 + w;        // 0..2559
    const size_t row0 = (size_t)wid * 32;

    f32x4 acc[2][5];
    #pragma unroll
    for (int t = 0; t < 2; ++t)
        #pragma unroll
        for (int ct = 0; ct < 5; ++ct)
            acc[t][ct] = (f32x4){0.f, 0.f, 0.f, 0.f};

    const float*  a0  = feat + (row0 + n) * D_ + q * 8;   // tile-0 row base
    const float*  a1  = a0 + (size_t)16 * D_;             // tile-1
    const ushort* bp0 = Wf + lane * 8;

    // A[buf][t*4 + kkl*2 + h] : float4 h of local-kk kkl of tile t
    float4 A[2][8];
    #pragma unroll
    for (int h = 0; h < 2; ++h) {
        #pragma unroll
        for (int kkl = 0; kkl < 2; ++kkl) {
            A[0][0 + kkl * 2 + h] = *(const float4*)(a0 + kkl * 32 + h * 4);
            A[0][4 + kkl * 2 + h] = *(const float4*)(a1 + kkl * 32 + h * 4);
        }
    }

    #pragma unroll
    for (int s = 0; s < 8; ++s) {
        const int cur = s & 1;
        if (s < 7) {   // prefetch next super-step (256 B per row)
            #pragma unroll
            for (int h = 0; h < 2; ++h) {
                #pragma unroll
                for (int kkl = 0; kkl < 2; ++kkl) {
                    A[cur ^ 1][0 + kkl * 2 + h] = *(const float4*)(a0 + (s + 1) * 64 + kkl * 32 + h * 4);
                    A[cur ^ 1][4 + kkl * 2 + h] = *(const float4*)(a1 + (s + 1) * 64 + kkl * 32 + h * 4);
                }
            }
        }
        #pragma unroll
        for (int kkl = 0; kkl < 2; ++kkl) {
            const int kk = s * 2 + kkl;
            // issue all 10 B loads before the MFMAs
            f16x8 B1[5], B2[5];
            #pragma unroll
            for (int ct = 0; ct < 5; ++ct) {
                const ushort* bp = bp0 + (size_t)(ct * NKK + kk) * FRAG;
                B1[ct] = *(const f16x8*)bp;
                B2[ct] = *(const f16x8*)(bp + PLANE_STRIDE);
            }
            // f16 2-term split of A for both tiles
            f16x8 a1f[2], a2f[2];
            #pragma unroll
            for (int t = 0; t < 2; ++t) {
                #pragma unroll
                for (int h = 0; h < 2; ++h) {
                    float4 f = A[cur][t * 4 + kkl * 2 + h];
                    float v[4] = {f.x, f.y, f.z, f.w};
                    #pragma unroll
                    for (int j = 0; j < 4; ++j) {
                        _Float16 hi = (_Float16)v[j];
                        a1f[t][h * 4 + j] = hi;
                        a2f[t][h * 4 + j] = (_Float16)(v[j] - (float)hi);
                    }
                }
            }
            #pragma unroll
            for (int ct = 0; ct < 5; ++ct) {
                acc[0][ct] = __builtin_amdgcn_mfma_f32_16x16x32_f16(a1f[0], B1[ct], acc[0][ct], 0, 0, 0);
                acc[0][ct] = __builtin_amdgcn_mfma_f32_16x16x32_f16(a2f[0], B1[ct], acc[0][ct], 0, 0, 0);
                acc[0][ct] = __builtin_amdgcn_mfma_f32_16x16x32_f16(a1f[0], B2[ct], acc[0][ct], 0, 0, 0);
                acc[0][ct] = __builtin_amdgcn_mfma_f32_16x16x32_f16(a2f[0], B2[ct], acc[0][ct], 0, 0, 0);
                acc[1][ct] = __builtin_amdgcn_mfma_f32_16x16x32_f16(a1f[1], B1[ct], acc[1][ct], 0, 0, 0);
                acc[1][ct] = __builtin_amdgcn_mfma_f32_16x16x32_f16(a2f[1], B1[ct], acc[1][ct], 0, 0, 0);
                acc[1][ct] = __builtin_amdgcn_mfma_f32_16x16x32_f16(a1f[1], B2[ct], acc[1][ct], 0, 0, 0);
                acc[1][ct] = __builtin_amdgcn_mfma_f32_16x16x32_f16(a2f[1], B2[ct], acc[1][ct], 0, 0, 0);
            }
        }
    }

    // ---- epilogue: bias + argmax + softmax + stores (per tile) ----
    #pragma unroll
    for (int t = 0; t < 2; ++t) {
        float x[5][4];
        #pragma unroll
        for (int ct = 0; ct < 5; ++ct) {
            int c = ct * 16 + n;
            bool valid = (c < C_);
            float bv = valid ? bias[c] : 0.f;
            #pragma unroll
            for (int r = 0; r < 4; ++r)
                x[ct][r] = valid ? (acc[t][ct][r] + bv) : -INFINITY;
        }
        float av[4]; int ai[4];
        #pragma unroll
        for (int r = 0; r < 4; ++r) {
            av[r] = x[0][r]; ai[r] = n;
            #pragma unroll
            for (int ct = 1; ct < 5; ++ct) {
                int c = ct * 16 + n;
                if (x[ct][r] > av[r]) { av[r] = x[ct][r]; ai[r] = c; }
            }
        }
        #pragma unroll
        for (int off = 8; off >= 1; off >>= 1) {
            #pragma unroll
            for (int r = 0; r < 4; ++r) {
                float ov = __shfl_xor(av[r], off, 16);
                int   oi = __shfl_xor(ai[r], off, 16);
                if (ov > av[r] || (ov == av[r] && oi < ai[r])) { av[r] = ov; ai[r] = oi; }
            }
        }
        float s[4] = {0.f, 0.f, 0.f, 0.f};
        #pragma unroll
        for (int ct = 0; ct < 5; ++ct)
            #pragma unroll
            for (int r = 0; r < 4; ++r) {
                x[ct][r] = __expf(x[ct][r] - av[r]);   // -INF -> 0
                s[r] += x[ct][r];
            }
        #pragma unroll
        for (int off = 8; off >= 1; off >>= 1)
            #pragma unroll
            for (int r = 0; r < 4; ++r) s[r] += __shfl_xor(s[r], off, 16);

        const size_t grow = row0 + t * 16 + q * 4;
        #pragma unroll
        for (int r = 0; r < 4; ++r) {
            float inv = 1.f / s[r];
            float* op = probs + (grow + r) * C_;
            #pragma unroll
            for (int ct = 0; ct < 5; ++ct) {
                int c = ct * 16 + n;
                if (c < C_) __builtin_nontemporal_store(x[ct][r] * inv, op + c);
            }
        }
        if (n == 0) {
            #pragma unroll
            for (int r = 0; r < 4; ++r) best[grow + r] = ai[r];
        }
    }
}

// CTC greedy collapse: merge repeats, drop blanks, pad -1 (as fp32)
__global__ __launch_bounds__(256) void ctc_decode(const int* __restrict__ best,
                                                  float* __restrict__ lab) {
    int b = blockIdx.x * 256 + threadIdx.x;
    if (b >= B_) return;
    const int* bp = best + (size_t)b * T_;
    float* op = lab + (size_t)b * PRED_;
    int prev = -1, pos = 0;
    for (int t = 0; t < T_; ++t) {
        int v = bp[t];
        if (v != BLANK_ && v != prev) {
            if (pos < PRED_) op[pos] = (float)v;
            ++pos;
        }
        prev = v;
    }
    for (int i = (pos < PRED_ ? pos : PRED_); i < PRED_; ++i) op[i] = -1.0f;
}

extern "C" void kernel_launch(void* const* d_in, const int* in_sizes, int n_in,
                              void* d_out, int out_size, void* d_ws, size_t ws_size,
                              hipStream_t stream) {
    const float* feat = (const float*)d_in[0];   // fp32 [1024,80,512]
    const float* W    = (const float*)d_in[1];   // fp32 [512,78]
    const float* bias = (const float*)d_in[2];   // fp32 [78]
    // d_in[3]=y, d_in[4]=times : unused
    float*  probs = (float*)d_out;
    float*  lab   = probs + (size_t)B_ * T_ * C_;
    ushort* Wf    = (ushort*)d_ws;                          // 163840 B
    int*    best  = (int*)((char*)d_ws + 2 * PLANE_STRIDE * sizeof(ushort));  // 81920 ints

    hipLaunchKernelGGL(prep_w, dim3(320), dim3(256), 0, stream, W, Wf);
    hipLaunchKernelGGL(gemm_fused, dim3(640), dim3(256), 0, stream,
                       feat, Wf, bias, probs, best);
    hipLaunchKernelGGL(ctc_decode, dim3(4), dim3(256), 0, stream, best, lab);
}